// Round 1
// baseline (641.785 us; speedup 1.0000x reference)
//
#include <hip/hip_runtime.h>
#include <hip/hip_bf16.h>

// SingleHeadCausalSelfAttention: B=8, S=2048, H=1024, causal, mask all-ones.
// Pipeline: cast->bf16, Q/K/V MFMA GEMMs (V stored transposed), per-batch
// causal scores (bf16, early-out above diagonal), in-place row softmax,
// causal-limited PV GEMM, final projection (fp32 out).

typedef __bf16 bf16x8 __attribute__((ext_vector_type(8)));
typedef float f32x4 __attribute__((ext_vector_type(4)));

static constexpr int HD = 1024;
static constexpr int BB = 8;
static constexpr int SS = 2048;

__device__ __forceinline__ unsigned short f2bf(float f) {
  unsigned u = __builtin_bit_cast(unsigned, f);
  return (unsigned short)((u + 0x7FFFu + ((u >> 16) & 1u)) >> 16);
}
__device__ __forceinline__ float bf2f(unsigned short v) {
  unsigned u = (unsigned)v << 16;
  return __builtin_bit_cast(float, u);
}
__device__ __forceinline__ f32x4 mfma16(bf16x8 a, bf16x8 b, f32x4 c) {
  return __builtin_amdgcn_mfma_f32_16x16x32_bf16(a, b, c, 0, 0, 0);
}

__global__ __launch_bounds__(256) void cast_kernel(
    const float* __restrict__ in, unsigned short* __restrict__ out, int n) {
  int idx = blockIdx.x * blockDim.x + threadIdx.x;
  int stride = gridDim.x * blockDim.x;
  for (int i = idx * 4; i < n; i += stride * 4) {
    float4 f = *reinterpret_cast<const float4*>(in + i);
    ushort4 o;
    o.x = f2bf(f.x); o.y = f2bf(f.y); o.z = f2bf(f.z); o.w = f2bf(f.w);
    *reinterpret_cast<ushort4*>(out + i) = o;
  }
}

// C[m][n] = sum_k A[m][k] * Bt[n][k]  (+ bias[n])
// TRANS: store C^T (C[n*ldc+m]); OUTF32: fp32 store; CAUSAL: k-loop limited to m0+64.
template <bool TRANS, bool OUTF32, bool BIAS, bool CAUSAL>
__global__ __launch_bounds__(256) void gemm_bt(
    const unsigned short* __restrict__ A, const unsigned short* __restrict__ Bt,
    const float* __restrict__ bias, void* __restrict__ Cp,
    int K, int lda, int ldb, int ldc,
    long long strideA, long long strideB, long long strideC) {
  __shared__ unsigned short As[64][40];
  __shared__ unsigned short Bs[64][40];
  const int tid = threadIdx.x;
  const int lane = tid & 63;
  const int wid = tid >> 6;
  const int wr = wid >> 1, wc = wid & 1;
  const int m0 = blockIdx.x * 64;
  const int n0 = blockIdx.y * 64;
  const long long b = blockIdx.z;

  A += b * strideA;
  Bt += b * strideB;
  unsigned short* C16 = reinterpret_cast<unsigned short*>(Cp) + b * strideC;
  float* C32 = reinterpret_cast<float*>(Cp) + b * strideC;

  const int kmax = CAUSAL ? min(K, m0 + 64) : K;

  f32x4 acc[2][2] = {};

  const int ldrow = tid >> 2;
  const int ldk = (tid & 3) * 8;
  const unsigned short* Arow = A + (long long)(m0 + ldrow) * lda + ldk;
  const unsigned short* Brow = Bt + (long long)(n0 + ldrow) * ldb + ldk;
  const int l16 = lane & 15;
  const int kg = (lane >> 4) * 8;

  for (int k0 = 0; k0 < kmax; k0 += 32) {
    __syncthreads();
    *reinterpret_cast<int4*>(&As[ldrow][ldk]) =
        *reinterpret_cast<const int4*>(Arow + k0);
    *reinterpret_cast<int4*>(&Bs[ldrow][ldk]) =
        *reinterpret_cast<const int4*>(Brow + k0);
    __syncthreads();
    bf16x8 a0 = *reinterpret_cast<const bf16x8*>(&As[wr * 32 + l16][kg]);
    bf16x8 a1 = *reinterpret_cast<const bf16x8*>(&As[wr * 32 + 16 + l16][kg]);
    bf16x8 b0 = *reinterpret_cast<const bf16x8*>(&Bs[wc * 32 + l16][kg]);
    bf16x8 b1 = *reinterpret_cast<const bf16x8*>(&Bs[wc * 32 + 16 + l16][kg]);
    acc[0][0] = mfma16(a0, b0, acc[0][0]);
    acc[0][1] = mfma16(a0, b1, acc[0][1]);
    acc[1][0] = mfma16(a1, b0, acc[1][0]);
    acc[1][1] = mfma16(a1, b1, acc[1][1]);
  }

  const int rr = (lane >> 4) * 4;
  const int cc = lane & 15;
#pragma unroll
  for (int r = 0; r < 2; ++r) {
#pragma unroll
    for (int c = 0; c < 2; ++c) {
      const int gn = n0 + wc * 32 + c * 16 + cc;
      const float bv = BIAS ? bias[gn] : 0.0f;
#pragma unroll
      for (int j = 0; j < 4; ++j) {
        const int gm = m0 + wr * 32 + r * 16 + rr + j;
        const float v = acc[r][c][j] + bv;
        if (OUTF32) {
          C32[(long long)gm * ldc + gn] = v;
        } else if (TRANS) {
          C16[(long long)gn * ldc + gm] = f2bf(v);
        } else {
          C16[(long long)gm * ldc + gn] = f2bf(v);
        }
      }
    }
  }
}

// scores[q][k] = (Q[q][:] . K[k][:]) / 32, causal+pad masked, bf16 out.
__global__ __launch_bounds__(256) void scores_kernel(
    const unsigned short* __restrict__ Q, const unsigned short* __restrict__ Km,
    const int* __restrict__ mask, unsigned short* __restrict__ S, float scale) {
  const int m0 = blockIdx.x * 64;
  const int n0 = blockIdx.y * 64;
  if (n0 > m0 + 63) return;  // fully above diagonal
  const long long b = blockIdx.z;
  Q += b * (long long)SS * HD;
  Km += b * (long long)SS * HD;
  mask += b * (long long)SS;
  S += b * (long long)SS * SS;

  __shared__ unsigned short As[64][40];
  __shared__ unsigned short Bs[64][40];
  const int tid = threadIdx.x;
  const int lane = tid & 63;
  const int wid = tid >> 6;
  const int wr = wid >> 1, wc = wid & 1;

  f32x4 acc[2][2] = {};
  const int ldrow = tid >> 2;
  const int ldk = (tid & 3) * 8;
  const unsigned short* Arow = Q + (long long)(m0 + ldrow) * HD + ldk;
  const unsigned short* Brow = Km + (long long)(n0 + ldrow) * HD + ldk;
  const int l16 = lane & 15;
  const int kg = (lane >> 4) * 8;

  for (int k0 = 0; k0 < HD; k0 += 32) {
    __syncthreads();
    *reinterpret_cast<int4*>(&As[ldrow][ldk]) =
        *reinterpret_cast<const int4*>(Arow + k0);
    *reinterpret_cast<int4*>(&Bs[ldrow][ldk]) =
        *reinterpret_cast<const int4*>(Brow + k0);
    __syncthreads();
    bf16x8 a0 = *reinterpret_cast<const bf16x8*>(&As[wr * 32 + l16][kg]);
    bf16x8 a1 = *reinterpret_cast<const bf16x8*>(&As[wr * 32 + 16 + l16][kg]);
    bf16x8 b0 = *reinterpret_cast<const bf16x8*>(&Bs[wc * 32 + l16][kg]);
    bf16x8 b1 = *reinterpret_cast<const bf16x8*>(&Bs[wc * 32 + 16 + l16][kg]);
    acc[0][0] = mfma16(a0, b0, acc[0][0]);
    acc[0][1] = mfma16(a0, b1, acc[0][1]);
    acc[1][0] = mfma16(a1, b0, acc[1][0]);
    acc[1][1] = mfma16(a1, b1, acc[1][1]);
  }

  const int rr = (lane >> 4) * 4;
  const int cc = lane & 15;
#pragma unroll
  for (int r = 0; r < 2; ++r) {
#pragma unroll
    for (int c = 0; c < 2; ++c) {
      const int gn = n0 + wc * 32 + c * 16 + cc;
      const int mk = mask[gn];
#pragma unroll
      for (int j = 0; j < 4; ++j) {
        const int gm = m0 + wr * 32 + r * 16 + rr + j;
        const bool dead = (gn > gm) || (mk == 0);
        S[(long long)gm * SS + gn] =
            dead ? (unsigned short)0xFF80u : f2bf(acc[r][c][j] * scale);
      }
    }
  }
}

// In-place per-row softmax over bf16 scores; writes zeros for k > q.
__global__ __launch_bounds__(256) void softmax_kernel(unsigned short* __restrict__ S) {
  const int q = blockIdx.x;
  const long long b = blockIdx.y;
  unsigned short* row = S + (b * SS + q) * (long long)SS;
  const int t = threadIdx.x;
  const int wid = t >> 6, lane = t & 63;
  __shared__ float red[4];
  __shared__ float brd[2];

  ushort4 v0 = *reinterpret_cast<const ushort4*>(&row[t * 8]);
  ushort4 v1 = *reinterpret_cast<const ushort4*>(&row[t * 8 + 4]);
  unsigned short raw[8] = {v0.x, v0.y, v0.z, v0.w, v1.x, v1.y, v1.z, v1.w};
  float f[8];
#pragma unroll
  for (int j = 0; j < 8; ++j) {
    const int k = t * 8 + j;
    f[j] = (k <= q) ? bf2f(raw[j]) : -INFINITY;
  }
  float m = -INFINITY;
#pragma unroll
  for (int j = 0; j < 8; ++j) m = fmaxf(m, f[j]);
  for (int off = 32; off > 0; off >>= 1) m = fmaxf(m, __shfl_xor(m, off));
  if (lane == 0) red[wid] = m;
  __syncthreads();
  if (t == 0) brd[0] = fmaxf(fmaxf(red[0], red[1]), fmaxf(red[2], red[3]));
  __syncthreads();
  m = brd[0];

  float e[8];
  float s = 0.0f;
#pragma unroll
  for (int j = 0; j < 8; ++j) {
    e[j] = __expf(f[j] - m);
    s += e[j];
  }
  for (int off = 32; off > 0; off >>= 1) s += __shfl_xor(s, off);
  __syncthreads();
  if (lane == 0) red[wid] = s;
  __syncthreads();
  if (t == 0) brd[1] = red[0] + red[1] + red[2] + red[3];
  __syncthreads();
  const float rinv = 1.0f / brd[1];

  unsigned short o[8];
#pragma unroll
  for (int j = 0; j < 8; ++j) o[j] = f2bf(e[j] * rinv);
  *reinterpret_cast<int4*>(&row[t * 8]) = *reinterpret_cast<int4*>(o);
}

extern "C" void kernel_launch(void* const* d_in, const int* in_sizes, int n_in,
                              void* d_out, int out_size, void* d_ws, size_t ws_size,
                              hipStream_t stream) {
  const float* x = (const float*)d_in[0];
  const int* amask = (const int*)d_in[1];
  const float* wq = (const float*)d_in[2];
  const float* bq = (const float*)d_in[3];
  const float* wk = (const float*)d_in[4];
  const float* bk = (const float*)d_in[5];
  const float* wv = (const float*)d_in[6];
  const float* bv = (const float*)d_in[7];
  const float* wo = (const float*)d_in[8];
  const float* bo = (const float*)d_in[9];
  float* out = (float*)d_out;

  const long long NX = (long long)BB * SS * HD;  // 16.7M elems
  char* p = (char*)d_ws;
  unsigned short* xb = (unsigned short*)p;   p += NX * 2;
  unsigned short* wqb = (unsigned short*)p;  p += (long long)HD * HD * 2;
  unsigned short* wkb = (unsigned short*)p;  p += (long long)HD * HD * 2;
  unsigned short* wvb = (unsigned short*)p;  p += (long long)HD * HD * 2;
  unsigned short* wob = (unsigned short*)p;  p += (long long)HD * HD * 2;
  unsigned short* Qb = (unsigned short*)p;   p += NX * 2;
  unsigned short* Kb = (unsigned short*)p;   p += NX * 2;
  unsigned short* Vtb = (unsigned short*)p;  p += NX * 2;  // [b][d][s]
  unsigned short* Sb = (unsigned short*)p;   p += (long long)BB * SS * SS * 2;
  unsigned short* AOb = xb;  // alias: x no longer needed after V projection

  cast_kernel<<<dim3(1024), 256, 0, stream>>>(x, xb, (int)NX);
  cast_kernel<<<dim3(256), 256, 0, stream>>>(wq, wqb, HD * HD);
  cast_kernel<<<dim3(256), 256, 0, stream>>>(wk, wkb, HD * HD);
  cast_kernel<<<dim3(256), 256, 0, stream>>>(wv, wvb, HD * HD);
  cast_kernel<<<dim3(256), 256, 0, stream>>>(wo, wob, HD * HD);

  // Q/K projections: [16384,1024] = xb @ w^T + b
  gemm_bt<false, false, true, false><<<dim3(256, 16, 1), 256, 0, stream>>>(
      xb, wqb, bq, Qb, HD, HD, HD, HD, 0, 0, 0);
  gemm_bt<false, false, true, false><<<dim3(256, 16, 1), 256, 0, stream>>>(
      xb, wkb, bk, Kb, HD, HD, HD, HD, 0, 0, 0);
  // V projection, stored transposed per batch: Vt[b][d][s]
  gemm_bt<true, false, true, false><<<dim3(32, 16, BB), 256, 0, stream>>>(
      xb, wvb, bv, Vtb, HD, HD, HD, SS,
      (long long)SS * HD, 0, (long long)SS * HD);

  // scores (bf16, causal-masked), then in-place row softmax
  scores_kernel<<<dim3(32, 32, BB), 256, 0, stream>>>(Qb, Kb, amask, Sb, 0.03125f);
  softmax_kernel<<<dim3(SS, BB), 256, 0, stream>>>(Sb);

  // attn_out[b][q][d] = P @ V  (K-loop causally limited)
  gemm_bt<false, false, false, true><<<dim3(32, 16, BB), 256, 0, stream>>>(
      Sb, Vtb, nullptr, AOb, SS, SS, SS, HD,
      (long long)SS * SS, (long long)SS * HD, (long long)SS * HD);

  // output projection: fp32 out = AO @ wo^T + bo
  gemm_bt<false, true, true, false><<<dim3(256, 16, 1), 256, 0, stream>>>(
      AOb, wob, bo, out, HD, HD, HD, HD, 0, 0, 0);
}

// Round 2
// 487.597 us; speedup vs baseline: 1.3162x; 1.3162x over previous
//
#include <hip/hip_runtime.h>
#include <hip/hip_bf16.h>

// SingleHeadCausalSelfAttention: B=8, S=2048, H=1024, causal, mask all-ones.
// R2: all GEMMs moved to m97 structure (128x128 tile, 4 waves, BK=32,
// global_load_lds width=16, linear LDS). Pipeline unchanged otherwise.

typedef __bf16 bf16x8 __attribute__((ext_vector_type(8)));
typedef float f32x4 __attribute__((ext_vector_type(4)));

static constexpr int HD = 1024;
static constexpr int BB = 8;
static constexpr int SS = 2048;

__device__ __forceinline__ unsigned short f2bf(float f) {
  unsigned u = __builtin_bit_cast(unsigned, f);
  return (unsigned short)((u + 0x7FFFu + ((u >> 16) & 1u)) >> 16);
}
__device__ __forceinline__ float bf2f(unsigned short v) {
  unsigned u = (unsigned)v << 16;
  return __builtin_bit_cast(float, u);
}
__device__ __forceinline__ f32x4 mfma16(bf16x8 a, bf16x8 b, f32x4 c) {
  return __builtin_amdgcn_mfma_f32_16x16x32_bf16(a, b, c, 0, 0, 0);
}
__device__ __forceinline__ void gload_lds16(const void* g, void* l) {
  __builtin_amdgcn_global_load_lds(
      (const __attribute__((address_space(1))) void*)g,
      (__attribute__((address_space(3))) void*)l, 16, 0, 0);
}

__global__ __launch_bounds__(256) void cast_kernel(
    const float* __restrict__ in, unsigned short* __restrict__ out, int n) {
  int idx = blockIdx.x * blockDim.x + threadIdx.x;
  int stride = gridDim.x * blockDim.x;
  for (int i = idx * 4; i < n; i += stride * 4) {
    float4 f = *reinterpret_cast<const float4*>(in + i);
    ushort4 o;
    o.x = f2bf(f.x); o.y = f2bf(f.y); o.z = f2bf(f.z); o.w = f2bf(f.w);
    *reinterpret_cast<ushort4*>(out + i) = o;
  }
}

// C[m][n] = sum_k A[m][k] * Bt[n][k] (+ bias[n])
// MODE 0: bf16 out. MODE 1: f32 out. MODE 2: bf16 transposed out (C[n][m]).
// MODE 3: scores (scale, causal+pad mask -> -inf, early-out above diagonal).
// CAUSAL: K-loop limited to m0+128 (PV GEMM).
template <int MODE, bool BIAS, bool CAUSAL>
__global__ __launch_bounds__(256) void gemm128(
    const unsigned short* __restrict__ A, const unsigned short* __restrict__ Bt,
    const float* __restrict__ bias, const int* __restrict__ mask,
    void* __restrict__ Cp, int K, int lda, int ldb, int ldc,
    long long strideA, long long strideB, long long strideC, float scale) {
  const int m0 = blockIdx.x * 128;
  const int n0 = blockIdx.y * 128;
  if (MODE == 3 && n0 > m0 + 127) return;  // fully above diagonal

  __shared__ unsigned short As[128 * 32];
  __shared__ unsigned short Bs[128 * 32];

  const int tid = threadIdx.x;
  const int lane = tid & 63;
  const int w = tid >> 6;
  const int wr = w >> 1, wc = w & 1;
  const long long b = blockIdx.z;
  A += b * strideA;
  Bt += b * strideB;
  const int* maskb = (MODE == 3) ? (mask + b * SS) : nullptr;

  const int kmax = CAUSAL ? min(K, m0 + 128) : K;
  f32x4 acc[4][4] = {};

  // staging: wave w covers rows [w*16, w*16+16) and [64+w*16, ...) of the tile
  const int lrow = lane >> 2;        // 0..15
  const int lcol = (lane & 3) * 8;   // 0,8,16,24 (bf16 elems)
  const unsigned short* Ag0 = A + (long long)(m0 + w * 16 + lrow) * lda + lcol;
  const unsigned short* Ag1 = Ag0 + (long long)64 * lda;
  const unsigned short* Bg0 = Bt + (long long)(n0 + w * 16 + lrow) * ldb + lcol;
  const unsigned short* Bg1 = Bg0 + (long long)64 * ldb;
  unsigned short* Al0 = &As[(w * 16) * 32];
  unsigned short* Al1 = &As[(64 + w * 16) * 32];
  unsigned short* Bl0 = &Bs[(w * 16) * 32];
  unsigned short* Bl1 = &Bs[(64 + w * 16) * 32];

  const int l16 = lane & 15;
  const int kg = (lane >> 4) * 8;

  for (int k0 = 0; k0 < kmax; k0 += 32) {
    __syncthreads();
    gload_lds16(Ag0 + k0, Al0);
    gload_lds16(Ag1 + k0, Al1);
    gload_lds16(Bg0 + k0, Bl0);
    gload_lds16(Bg1 + k0, Bl1);
    __syncthreads();
    bf16x8 af[4], bfr[4];
#pragma unroll
    for (int i = 0; i < 4; ++i)
      af[i] = *reinterpret_cast<const bf16x8*>(
          &As[(wr * 64 + i * 16 + l16) * 32 + kg]);
#pragma unroll
    for (int i = 0; i < 4; ++i)
      bfr[i] = *reinterpret_cast<const bf16x8*>(
          &Bs[(wc * 64 + i * 16 + l16) * 32 + kg]);
#pragma unroll
    for (int i = 0; i < 4; ++i)
#pragma unroll
      for (int c = 0; c < 4; ++c)
        acc[i][c] = mfma16(af[i], bfr[c], acc[i][c]);
  }

  unsigned short* C16 = reinterpret_cast<unsigned short*>(Cp) + b * strideC;
  float* C32 = reinterpret_cast<float*>(Cp) + b * strideC;
  const int rr = (lane >> 4) * 4;
  const int cc = lane & 15;
#pragma unroll
  for (int i = 0; i < 4; ++i) {
#pragma unroll
    for (int c = 0; c < 4; ++c) {
      const int gn = n0 + wc * 64 + c * 16 + cc;
      const float bv = BIAS ? bias[gn] : 0.0f;
      const int mk = (MODE == 3) ? maskb[gn] : 1;
#pragma unroll
      for (int j = 0; j < 4; ++j) {
        const int gm = m0 + wr * 64 + i * 16 + rr + j;
        const float v = acc[i][c][j] + bv;
        if (MODE == 1) {
          C32[(long long)gm * ldc + gn] = v;
        } else if (MODE == 2) {
          C16[(long long)gn * ldc + gm] = f2bf(v);
        } else if (MODE == 3) {
          const bool dead = (gn > gm) || (mk == 0);
          C16[(long long)gm * ldc + gn] =
              dead ? (unsigned short)0xFF80u : f2bf(v * scale);
        } else {
          C16[(long long)gm * ldc + gn] = f2bf(v);
        }
      }
    }
  }
}

// In-place per-row softmax over bf16 scores; writes zeros for k > q.
__global__ __launch_bounds__(256) void softmax_kernel(unsigned short* __restrict__ S) {
  const int q = blockIdx.x;
  const long long b = blockIdx.y;
  unsigned short* row = S + (b * SS + q) * (long long)SS;
  const int t = threadIdx.x;
  const int wid = t >> 6, lane = t & 63;
  __shared__ float red[4];
  __shared__ float brd[2];

  ushort4 v0 = *reinterpret_cast<const ushort4*>(&row[t * 8]);
  ushort4 v1 = *reinterpret_cast<const ushort4*>(&row[t * 8 + 4]);
  unsigned short raw[8] = {v0.x, v0.y, v0.z, v0.w, v1.x, v1.y, v1.z, v1.w};
  float f[8];
#pragma unroll
  for (int j = 0; j < 8; ++j) {
    const int k = t * 8 + j;
    f[j] = (k <= q) ? bf2f(raw[j]) : -INFINITY;
  }
  float m = -INFINITY;
#pragma unroll
  for (int j = 0; j < 8; ++j) m = fmaxf(m, f[j]);
  for (int off = 32; off > 0; off >>= 1) m = fmaxf(m, __shfl_xor(m, off));
  if (lane == 0) red[wid] = m;
  __syncthreads();
  if (t == 0) brd[0] = fmaxf(fmaxf(red[0], red[1]), fmaxf(red[2], red[3]));
  __syncthreads();
  m = brd[0];

  float e[8];
  float s = 0.0f;
#pragma unroll
  for (int j = 0; j < 8; ++j) {
    e[j] = __expf(f[j] - m);
    s += e[j];
  }
  for (int off = 32; off > 0; off >>= 1) s += __shfl_xor(s, off);
  __syncthreads();
  if (lane == 0) red[wid] = s;
  __syncthreads();
  if (t == 0) brd[1] = red[0] + red[1] + red[2] + red[3];
  __syncthreads();
  const float rinv = 1.0f / brd[1];

  unsigned short o[8];
#pragma unroll
  for (int j = 0; j < 8; ++j) o[j] = f2bf(e[j] * rinv);
  *reinterpret_cast<int4*>(&row[t * 8]) = *reinterpret_cast<int4*>(o);
}

extern "C" void kernel_launch(void* const* d_in, const int* in_sizes, int n_in,
                              void* d_out, int out_size, void* d_ws, size_t ws_size,
                              hipStream_t stream) {
  const float* x = (const float*)d_in[0];
  const int* amask = (const int*)d_in[1];
  const float* wq = (const float*)d_in[2];
  const float* bq = (const float*)d_in[3];
  const float* wk = (const float*)d_in[4];
  const float* bk = (const float*)d_in[5];
  const float* wv = (const float*)d_in[6];
  const float* bv = (const float*)d_in[7];
  const float* wo = (const float*)d_in[8];
  const float* bo = (const float*)d_in[9];
  float* out = (float*)d_out;

  const long long NX = (long long)BB * SS * HD;  // 16.7M elems
  const long long SH = (long long)SS * HD;
  char* p = (char*)d_ws;
  unsigned short* xb = (unsigned short*)p;   p += NX * 2;
  unsigned short* wqb = (unsigned short*)p;  p += (long long)HD * HD * 2;
  unsigned short* wkb = (unsigned short*)p;  p += (long long)HD * HD * 2;
  unsigned short* wvb = (unsigned short*)p;  p += (long long)HD * HD * 2;
  unsigned short* wob = (unsigned short*)p;  p += (long long)HD * HD * 2;
  unsigned short* Qb = (unsigned short*)p;   p += NX * 2;
  unsigned short* Kb = (unsigned short*)p;   p += NX * 2;
  unsigned short* Vtb = (unsigned short*)p;  p += NX * 2;  // [b][d][s]
  unsigned short* Sb = (unsigned short*)p;   p += (long long)BB * SS * SS * 2;
  unsigned short* AOb = xb;  // alias: x no longer needed after V projection

  cast_kernel<<<dim3(1024), 256, 0, stream>>>(x, xb, (int)NX);
  cast_kernel<<<dim3(256), 256, 0, stream>>>(wq, wqb, HD * HD);
  cast_kernel<<<dim3(256), 256, 0, stream>>>(wk, wkb, HD * HD);
  cast_kernel<<<dim3(256), 256, 0, stream>>>(wv, wvb, HD * HD);
  cast_kernel<<<dim3(256), 256, 0, stream>>>(wo, wob, HD * HD);

  // Q/K projections: [16384,1024] = xb @ w^T + b
  gemm128<0, true, false><<<dim3(128, 8, 1), 256, 0, stream>>>(
      xb, wqb, bq, nullptr, Qb, HD, HD, HD, HD, 0, 0, 0, 1.0f);
  gemm128<0, true, false><<<dim3(128, 8, 1), 256, 0, stream>>>(
      xb, wkb, bk, nullptr, Kb, HD, HD, HD, HD, 0, 0, 0, 1.0f);
  // V projection, stored transposed per batch: Vt[b][d][s]
  gemm128<2, true, false><<<dim3(16, 8, BB), 256, 0, stream>>>(
      xb, wvb, bv, nullptr, Vtb, HD, HD, HD, SS, SH, 0, SH, 1.0f);

  // scores (bf16, causal-masked, scaled), then in-place row softmax
  gemm128<3, false, false><<<dim3(16, 16, BB), 256, 0, stream>>>(
      Qb, Kb, nullptr, amask, Sb, HD, HD, HD, SS, SH, SH,
      (long long)SS * SS, 0.03125f);
  softmax_kernel<<<dim3(SS, BB), 256, 0, stream>>>(Sb);

  // attn_out[b][q][d] = P @ V  (K-loop causally limited)
  gemm128<0, false, true><<<dim3(16, 8, BB), 256, 0, stream>>>(
      Sb, Vtb, nullptr, nullptr, AOb, SS, SS, SS, HD,
      (long long)SS * SS, SH, SH, 1.0f);

  // output projection: fp32 out = AO @ wo^T + bo
  gemm128<1, true, false><<<dim3(128, 8, 1), 256, 0, stream>>>(
      AOb, wob, bo, nullptr, out, HD, HD, HD, HD, 0, 0, 0, 1.0f);
}

// Round 3
// 413.046 us; speedup vs baseline: 1.5538x; 1.1805x over previous
//
#include <hip/hip_runtime.h>
#include <hip/hip_bf16.h>

// SingleHeadCausalSelfAttention: B=8, S=2048, H=1024, causal, mask all-ones.
// R3: QKV fused (N=3072) GEMM; n-fastest + XCD-chunked block order on the
// projections; causal scores via uniform triangular pairing; PV via m-pairing
// (uniform K-work per block). Inner loop = m97 structure (128x128, BK=32,
// global_load_lds width=16, linear LDS).

typedef __bf16 bf16x8 __attribute__((ext_vector_type(8)));
typedef float f32x4 __attribute__((ext_vector_type(4)));

static constexpr int HD = 1024;
static constexpr int BB = 8;
static constexpr int SS = 2048;
static constexpr long long SH = (long long)SS * HD;

__device__ __forceinline__ unsigned short f2bf(float f) {
  unsigned u = __builtin_bit_cast(unsigned, f);
  return (unsigned short)((u + 0x7FFFu + ((u >> 16) & 1u)) >> 16);
}
__device__ __forceinline__ float bf2f(unsigned short v) {
  unsigned u = (unsigned)v << 16;
  return __builtin_bit_cast(float, u);
}
__device__ __forceinline__ f32x4 mfma16(bf16x8 a, bf16x8 b, f32x4 c) {
  return __builtin_amdgcn_mfma_f32_16x16x32_bf16(a, b, c, 0, 0, 0);
}
__device__ __forceinline__ void gload_lds16(const void* g, void* l) {
  __builtin_amdgcn_global_load_lds(
      (const __attribute__((address_space(1))) void*)g,
      (__attribute__((address_space(3))) void*)l, 16, 0, 0);
}

__global__ __launch_bounds__(256) void cast_kernel(
    const float* __restrict__ in, unsigned short* __restrict__ out, int n) {
  int idx = blockIdx.x * blockDim.x + threadIdx.x;
  int stride = gridDim.x * blockDim.x;
  for (int i = idx * 4; i < n; i += stride * 4) {
    float4 f = *reinterpret_cast<const float4*>(in + i);
    ushort4 o;
    o.x = f2bf(f.x); o.y = f2bf(f.y); o.z = f2bf(f.z); o.w = f2bf(f.w);
    *reinterpret_cast<ushort4*>(out + i) = o;
  }
}

// Shared m97-structure K-loop: 128x128 tile, BK=32, 4 waves, 4x4 acc.
// LDS layouts As/Bs: [128][32] linear bf16.
struct TileCtx {
  const unsigned short *Ag0, *Ag1, *Bg0, *Bg1;  // per-lane global srcs (k0=0)
  unsigned short *Al0, *Al1, *Bl0, *Bl1;        // wave-uniform LDS dsts
  const unsigned short *As, *Bs;
  int wr, wc, l16, kg;
  int lda, ldb;
};

__device__ __forceinline__ void tile_setup(
    TileCtx& c, const unsigned short* A, const unsigned short* B,
    int m0, int n0, int lda, int ldb,
    unsigned short* As, unsigned short* Bs) {
  const int tid = threadIdx.x;
  const int lane = tid & 63;
  const int w = tid >> 6;
  const int lrow = lane >> 2;
  const int lcol = (lane & 3) * 8;
  c.Ag0 = A + (long long)(m0 + w * 16 + lrow) * lda + lcol;
  c.Ag1 = c.Ag0 + (long long)64 * lda;
  c.Bg0 = B + (long long)(n0 + w * 16 + lrow) * ldb + lcol;
  c.Bg1 = c.Bg0 + (long long)64 * ldb;
  c.Al0 = &As[(w * 16) * 32];
  c.Al1 = &As[(64 + w * 16) * 32];
  c.Bl0 = &Bs[(w * 16) * 32];
  c.Bl1 = &Bs[(64 + w * 16) * 32];
  c.As = As; c.Bs = Bs;
  c.wr = w >> 1; c.wc = w & 1;
  c.l16 = lane & 15; c.kg = (lane >> 4) * 8;
  c.lda = lda; c.ldb = ldb;
}

__device__ __forceinline__ void tile_kloop(const TileCtx& c, int kmax,
                                           f32x4 acc[4][4]) {
  for (int k0 = 0; k0 < kmax; k0 += 32) {
    __syncthreads();
    gload_lds16(c.Ag0 + k0, c.Al0);
    gload_lds16(c.Ag1 + k0, c.Al1);
    gload_lds16(c.Bg0 + k0, c.Bl0);
    gload_lds16(c.Bg1 + k0, c.Bl1);
    __syncthreads();
    bf16x8 af[4], bfr[4];
#pragma unroll
    for (int i = 0; i < 4; ++i)
      af[i] = *reinterpret_cast<const bf16x8*>(
          &c.As[(c.wr * 64 + i * 16 + c.l16) * 32 + c.kg]);
#pragma unroll
    for (int i = 0; i < 4; ++i)
      bfr[i] = *reinterpret_cast<const bf16x8*>(
          &c.Bs[(c.wc * 64 + i * 16 + c.l16) * 32 + c.kg]);
#pragma unroll
    for (int i = 0; i < 4; ++i)
#pragma unroll
      for (int cc = 0; cc < 4; ++cc)
        acc[i][cc] = mfma16(af[i], bfr[cc], acc[i][cc]);
  }
}

// ---- fused QKV projection: C[16384][3072] routed to Qb / Kb / Vt ----
__global__ __launch_bounds__(256) void qkv_kernel(
    const unsigned short* __restrict__ X, const unsigned short* __restrict__ W,
    const float* __restrict__ bq, const float* __restrict__ bk,
    const float* __restrict__ bv, unsigned short* __restrict__ Qb,
    unsigned short* __restrict__ Kb, unsigned short* __restrict__ Vt) {
  __shared__ unsigned short As[128 * 32];
  __shared__ unsigned short Bs[128 * 32];
  // grid (24, 128), x fastest; XCD-chunked swizzle over 3072 blocks
  const int lin = blockIdx.y * 24 + blockIdx.x;
  const int swz = (lin & 7) * 384 + (lin >> 3);
  const int m0 = (swz / 24) * 128;
  const int n0 = (swz % 24) * 128;

  TileCtx c;
  tile_setup(c, X, W, m0, n0, HD, HD, As, Bs);
  f32x4 acc[4][4] = {};
  tile_kloop(c, HD, acc);

  const int lane = threadIdx.x & 63;
  const int rr = (lane >> 4) * 4;
  const int ccl = lane & 15;
#pragma unroll
  for (int i = 0; i < 4; ++i) {
#pragma unroll
    for (int cc = 0; cc < 4; ++cc) {
      const int gn = n0 + c.wc * 64 + cc * 16 + ccl;
      float bias;
      if (gn < 1024) bias = bq[gn];
      else if (gn < 2048) bias = bk[gn - 1024];
      else bias = bv[gn - 2048];
#pragma unroll
      for (int j = 0; j < 4; ++j) {
        const int gm = m0 + c.wr * 64 + i * 16 + rr + j;
        const unsigned short v = f2bf(acc[i][cc][j] + bias);
        if (gn < 1024) {
          Qb[(long long)gm * HD + gn] = v;
        } else if (gn < 2048) {
          Kb[(long long)gm * HD + (gn - 1024)] = v;
        } else {
          const int b = gm >> 11, s = gm & 2047, d = gn - 2048;
          Vt[b * SH + (long long)d * SS + s] = v;
        }
      }
    }
  }
}

// ---- causal scores: uniform triangular pairing, grid (17, 8, BB) ----
__global__ __launch_bounds__(256) void scores_kernel(
    const unsigned short* __restrict__ Q, const unsigned short* __restrict__ Km,
    const int* __restrict__ mask, unsigned short* __restrict__ S) {
  __shared__ unsigned short As[128 * 32];
  __shared__ unsigned short Bs[128 * 32];
  const int t = blockIdx.x, p = blockIdx.y;
  const long long b = blockIdx.z;
  const int i = (t <= p) ? p : 15 - p;
  const int j = (t <= p) ? t : t - p - 1;
  const int m0 = i * 128, n0 = j * 128;

  TileCtx c;
  tile_setup(c, Q + b * SH, Km + b * SH, m0, n0, HD, HD, As, Bs);
  f32x4 acc[4][4] = {};
  tile_kloop(c, HD, acc);

  unsigned short* Sb = S + b * (long long)SS * SS;
  const int* mb = mask + b * SS;
  const int lane = threadIdx.x & 63;
  const int rr = (lane >> 4) * 4;
  const int ccl = lane & 15;
#pragma unroll
  for (int i2 = 0; i2 < 4; ++i2) {
#pragma unroll
    for (int cc = 0; cc < 4; ++cc) {
      const int gn = n0 + c.wc * 64 + cc * 16 + ccl;
      const int mk = mb[gn];
#pragma unroll
      for (int j2 = 0; j2 < 4; ++j2) {
        const int gm = m0 + c.wr * 64 + i2 * 16 + rr + j2;
        const bool dead = (gn > gm) || (mk == 0);
        Sb[(long long)gm * SS + gn] =
            dead ? (unsigned short)0xFF80u : f2bf(acc[i2][cc][j2] * 0.03125f);
      }
    }
  }
}

// ---- PV with m-pairing: grid (8, 8, BB), uniform K-work per block ----
__global__ __launch_bounds__(256) void pv_kernel(
    const unsigned short* __restrict__ S, const unsigned short* __restrict__ Vt,
    unsigned short* __restrict__ AO) {
  __shared__ unsigned short As[128 * 32];
  __shared__ unsigned short Bs[128 * 32];
  const int p = blockIdx.x;
  const int n0 = blockIdx.y * 128;
  const long long b = blockIdx.z;
  const unsigned short* Sb = S + b * (long long)SS * SS;
  const unsigned short* Vb = Vt + b * SH;
  const int lane = threadIdx.x & 63;
  const int rr = (lane >> 4) * 4;
  const int ccl = lane & 15;

#pragma unroll
  for (int pass = 0; pass < 2; ++pass) {
    const int mi = pass ? 15 - p : p;
    const int m0 = mi * 128;
    const int kmax = m0 + 128;
    TileCtx c;
    tile_setup(c, Sb, Vb, m0, n0, SS, SS, As, Bs);
    f32x4 acc[4][4] = {};
    tile_kloop(c, kmax, acc);
#pragma unroll
    for (int i = 0; i < 4; ++i) {
#pragma unroll
      for (int cc = 0; cc < 4; ++cc) {
        const int gn = n0 + c.wc * 64 + cc * 16 + ccl;
#pragma unroll
        for (int j = 0; j < 4; ++j) {
          const int gm = m0 + c.wr * 64 + i * 16 + rr + j;
          AO[(b * SS + gm) * (long long)HD + gn] = f2bf(acc[i][cc][j]);
        }
      }
    }
  }
}

// ---- output projection: f32 out, grid (8, 128) n-fastest + XCD swizzle ----
__global__ __launch_bounds__(256) void oproj_kernel(
    const unsigned short* __restrict__ AO, const unsigned short* __restrict__ W,
    const float* __restrict__ bo, float* __restrict__ out) {
  __shared__ unsigned short As[128 * 32];
  __shared__ unsigned short Bs[128 * 32];
  const int lin = blockIdx.y * 8 + blockIdx.x;
  const int swz = (lin & 7) * 128 + (lin >> 3);
  const int m0 = (swz / 8) * 128;
  const int n0 = (swz % 8) * 128;

  TileCtx c;
  tile_setup(c, AO, W, m0, n0, HD, HD, As, Bs);
  f32x4 acc[4][4] = {};
  tile_kloop(c, HD, acc);

  const int lane = threadIdx.x & 63;
  const int rr = (lane >> 4) * 4;
  const int ccl = lane & 15;
#pragma unroll
  for (int i = 0; i < 4; ++i) {
#pragma unroll
    for (int cc = 0; cc < 4; ++cc) {
      const int gn = n0 + c.wc * 64 + cc * 16 + ccl;
      const float bias = bo[gn];
#pragma unroll
      for (int j = 0; j < 4; ++j) {
        const int gm = m0 + c.wr * 64 + i * 16 + rr + j;
        out[(long long)gm * HD + gn] = acc[i][cc][j] + bias;
      }
    }
  }
}

// In-place per-row softmax over bf16 scores; writes zeros for k > q.
__global__ __launch_bounds__(256) void softmax_kernel(unsigned short* __restrict__ S) {
  const int q = blockIdx.x;
  const long long b = blockIdx.y;
  unsigned short* row = S + (b * SS + q) * (long long)SS;
  const int t = threadIdx.x;
  const int wid = t >> 6, lane = t & 63;
  __shared__ float red[4];
  __shared__ float brd[2];

  ushort4 v0 = *reinterpret_cast<const ushort4*>(&row[t * 8]);
  ushort4 v1 = *reinterpret_cast<const ushort4*>(&row[t * 8 + 4]);
  unsigned short raw[8] = {v0.x, v0.y, v0.z, v0.w, v1.x, v1.y, v1.z, v1.w};
  float f[8];
#pragma unroll
  for (int j = 0; j < 8; ++j) {
    const int k = t * 8 + j;
    f[j] = (k <= q) ? bf2f(raw[j]) : -INFINITY;
  }
  float m = -INFINITY;
#pragma unroll
  for (int j = 0; j < 8; ++j) m = fmaxf(m, f[j]);
  for (int off = 32; off > 0; off >>= 1) m = fmaxf(m, __shfl_xor(m, off));
  if (lane == 0) red[wid] = m;
  __syncthreads();
  if (t == 0) brd[0] = fmaxf(fmaxf(red[0], red[1]), fmaxf(red[2], red[3]));
  __syncthreads();
  m = brd[0];

  float e[8];
  float s = 0.0f;
#pragma unroll
  for (int j = 0; j < 8; ++j) {
    e[j] = __expf(f[j] - m);
    s += e[j];
  }
  for (int off = 32; off > 0; off >>= 1) s += __shfl_xor(s, off);
  __syncthreads();
  if (lane == 0) red[wid] = s;
  __syncthreads();
  if (t == 0) brd[1] = red[0] + red[1] + red[2] + red[3];
  __syncthreads();
  const float rinv = 1.0f / brd[1];

  unsigned short o[8];
#pragma unroll
  for (int j = 0; j < 8; ++j) o[j] = f2bf(e[j] * rinv);
  *reinterpret_cast<int4*>(&row[t * 8]) = *reinterpret_cast<int4*>(o);
}

extern "C" void kernel_launch(void* const* d_in, const int* in_sizes, int n_in,
                              void* d_out, int out_size, void* d_ws, size_t ws_size,
                              hipStream_t stream) {
  const float* x = (const float*)d_in[0];
  const int* amask = (const int*)d_in[1];
  const float* wq = (const float*)d_in[2];
  const float* bq = (const float*)d_in[3];
  const float* wk = (const float*)d_in[4];
  const float* bk = (const float*)d_in[5];
  const float* wv = (const float*)d_in[6];
  const float* bv = (const float*)d_in[7];
  const float* wo = (const float*)d_in[8];
  const float* bo = (const float*)d_in[9];
  float* out = (float*)d_out;

  const long long NX = (long long)BB * SS * HD;  // 16.7M elems
  char* p = (char*)d_ws;
  unsigned short* xb = (unsigned short*)p;     p += NX * 2;
  unsigned short* wqkvb = (unsigned short*)p;  p += 3LL * HD * HD * 2;
  unsigned short* wob = (unsigned short*)p;    p += (long long)HD * HD * 2;
  unsigned short* Qb = (unsigned short*)p;     p += NX * 2;
  unsigned short* Kb = (unsigned short*)p;     p += NX * 2;
  unsigned short* Vtb = (unsigned short*)p;    p += NX * 2;  // [b][d][s]
  unsigned short* Sb = (unsigned short*)p;     p += (long long)BB * SS * SS * 2;
  unsigned short* AOb = xb;  // alias: x no longer needed after QKV projection

  cast_kernel<<<dim3(2048), 256, 0, stream>>>(x, xb, (int)NX);
  cast_kernel<<<dim3(256), 256, 0, stream>>>(wq, wqkvb, HD * HD);
  cast_kernel<<<dim3(256), 256, 0, stream>>>(wk, wqkvb + HD * HD, HD * HD);
  cast_kernel<<<dim3(256), 256, 0, stream>>>(wv, wqkvb + 2 * HD * HD, HD * HD);
  cast_kernel<<<dim3(256), 256, 0, stream>>>(wo, wob, HD * HD);

  qkv_kernel<<<dim3(24, 128), 256, 0, stream>>>(
      xb, wqkvb, bq, bk, bv, Qb, Kb, Vtb);

  scores_kernel<<<dim3(17, 8, BB), 256, 0, stream>>>(Qb, Kb, amask, Sb);
  softmax_kernel<<<dim3(SS, BB), 256, 0, stream>>>(Sb);
  pv_kernel<<<dim3(8, 8, BB), 256, 0, stream>>>(Sb, Vtb, AOb);

  oproj_kernel<<<dim3(8, 128), 256, 0, stream>>>(AOb, wob, bo, out);
}

// Round 4
// 385.872 us; speedup vs baseline: 1.6632x; 1.0704x over previous
//
#include <hip/hip_runtime.h>
#include <hip/hip_bf16.h>

// SingleHeadCausalSelfAttention B=8 S=2048 H=1024 causal.
// R4: all GEMMs on a 256x256 (BK=64) 8-wave 8-phase pipeline (m201-style):
// T2 st_16x32 LDS swizzle (linear gload_lds dest + pre-swizzled global src),
// T3/T4 counted vmcnt(2) at phases 4/8 only, T5 setprio around MFMA.
// V^T produced by swapped GEMM (A=Wv, B=x) for coalesced writes.

typedef __bf16 bf16x8 __attribute__((ext_vector_type(8)));
typedef float f32x4 __attribute__((ext_vector_type(4)));

static constexpr int HD = 1024;
static constexpr int BB = 8;
static constexpr int SS = 2048;
static constexpr long long SH = (long long)SS * HD;

__device__ __forceinline__ unsigned short f2bf(float f) {
  unsigned u = __builtin_bit_cast(unsigned, f);
  return (unsigned short)((u + 0x7FFFu + ((u >> 16) & 1u)) >> 16);
}
__device__ __forceinline__ float bf2f(unsigned short v) {
  unsigned u = (unsigned)v << 16;
  return __builtin_bit_cast(float, u);
}
__device__ __forceinline__ f32x4 mfma16(bf16x8 a, bf16x8 b, f32x4 c) {
  return __builtin_amdgcn_mfma_f32_16x16x32_bf16(a, b, c, 0, 0, 0);
}
__device__ __forceinline__ void gload_lds16(const void* g, void* l) {
  __builtin_amdgcn_global_load_lds(
      (const __attribute__((address_space(1))) void*)g,
      (__attribute__((address_space(3))) void*)l, 16, 0, 0);
}

#define WAIT_LGKM0() do { asm volatile("s_waitcnt lgkmcnt(0)" ::: "memory"); \
  __builtin_amdgcn_sched_barrier(0); } while (0)
#define WAIT_VM(n) do { asm volatile("s_waitcnt vmcnt(" #n ")" ::: "memory"); \
  __builtin_amdgcn_sched_barrier(0); } while (0)

// swizzled LDS read: logical (row, colbyte) -> byte ^ ((row&4)<<3)
__device__ __forceinline__ bf16x8 read_frag(const unsigned short* tile, int row,
                                            int colb) {
  int byte = row * 128 + colb;
  byte ^= (row & 4) << 3;
  return *reinterpret_cast<const bf16x8*>(
      reinterpret_cast<const char*>(tile) + byte);
}

// stage one half-tile (128 rows x 64 cols bf16) of a 256x64 K-tile.
// pM = per-thread base: M + (t0 + (tid>>3))*ld + colg, colg pre-swizzled.
__device__ __forceinline__ void stage_half(const unsigned short* pM,
                                           long long ld, long long kt,
                                           unsigned short* tile, int h,
                                           int wid) {
  const unsigned short* s = pM + (long long)(h * 128) * ld + kt;
  gload_lds16(s, tile + h * 8192 + wid * 512);
  gload_lds16(s + 64 * ld, tile + h * 8192 + 4096 + wid * 512);
}

template <int Q>
__device__ __forceinline__ void ds_a(const unsigned short* At, int rA, int cb,
                                     bf16x8 af[2][2]) {
  af[0][0] = read_frag(At, rA + (2 * Q) * 16, cb);
  af[0][1] = read_frag(At, rA + (2 * Q) * 16, 64 + cb);
  af[1][0] = read_frag(At, rA + (2 * Q + 1) * 16, cb);
  af[1][1] = read_frag(At, rA + (2 * Q + 1) * 16, 64 + cb);
}
__device__ __forceinline__ void ds_b(const unsigned short* Bt, int rB, int cb,
                                     bf16x8 B[4][2]) {
#pragma unroll
  for (int ni = 0; ni < 4; ++ni) {
    B[ni][0] = read_frag(Bt, rB + ni * 16, cb);
    B[ni][1] = read_frag(Bt, rB + ni * 16, 64 + cb);
  }
}
template <int Q>
__device__ __forceinline__ void mfma_q(const bf16x8 af[2][2],
                                       const bf16x8 B[4][2], f32x4 acc[8][4]) {
#pragma unroll
  for (int m2 = 0; m2 < 2; ++m2)
#pragma unroll
    for (int ni = 0; ni < 4; ++ni) {
      acc[2 * Q + m2][ni] = mfma16(af[m2][0], B[ni][0], acc[2 * Q + m2][ni]);
      acc[2 * Q + m2][ni] = mfma16(af[m2][1], B[ni][1], acc[2 * Q + m2][ni]);
    }
}

#define PH_TAIL(QN, BRG) do { \
  __builtin_amdgcn_s_barrier(); \
  WAIT_LGKM0(); \
  __builtin_amdgcn_s_setprio(1); \
  mfma_q<QN>(af, BRG, acc); \
  __builtin_amdgcn_s_setprio(0); \
  __builtin_amdgcn_s_barrier(); \
} while (0)

// 256x256 output tile over K = NT*64 (NT even, >=2).
__device__ __forceinline__ void run_tile(
    const unsigned short* pA, const unsigned short* pB, long long lda,
    long long ldb, int NT, unsigned short* As0, unsigned short* As1,
    unsigned short* Bs0, unsigned short* Bs1, int wid, int rA, int rB, int cb,
    f32x4 acc[8][4]) {
  bf16x8 BA[4][2], BB[4][2], af[2][2];
  // prologue: T0 -> buf0 (A,B); B(T1) -> buf1.B
  stage_half(pA, lda, 0, As0, 0, wid);
  stage_half(pA, lda, 0, As0, 1, wid);
  stage_half(pB, ldb, 0, Bs0, 0, wid);
  stage_half(pB, ldb, 0, Bs0, 1, wid);
  stage_half(pB, ldb, 64, Bs1, 0, wid);
  stage_half(pB, ldb, 64, Bs1, 1, wid);
  WAIT_VM(4);
  __builtin_amdgcn_s_barrier();
  ds_b(Bs0, rB, cb, BA);
  WAIT_LGKM0();
  __builtin_amdgcn_s_barrier();

  const int NITER = NT / 2 - 1;
  for (int i = 0; i < NITER; ++i) {
    const long long kA1 = (long long)(2 * i + 1) * 64;
    const long long kN2 = (long long)(2 * i + 2) * 64;
    const long long kB3 = (long long)(2 * i + 3) * 64;
    // P1..P3: compute T2i (buf0) w/ BA; stage buf1.A <- A(T2i+1), buf0.B <- B(T2i+2)
    ds_a<0>(As0, rA, cb, af); stage_half(pA, lda, kA1, As1, 0, wid); PH_TAIL(0, BA);
    ds_a<1>(As0, rA, cb, af); stage_half(pA, lda, kA1, As1, 1, wid); PH_TAIL(1, BA);
    ds_a<2>(As0, rA, cb, af); stage_half(pB, ldb, kN2, Bs0, 0, wid); PH_TAIL(2, BA);
    // P4: ensure buf1 (A of T2i+1, B of T2i+1) landed; read B(T2i+1) -> BB
    WAIT_VM(2);
    ds_a<3>(As0, rA, cb, af); ds_b(Bs1, rB, cb, BB);
    stage_half(pB, ldb, kN2, Bs0, 1, wid); PH_TAIL(3, BA);
    // P5..P7: compute T2i+1 (buf1) w/ BB; stage buf0.A <- A(T2i+2), buf1.B <- B(T2i+3)
    ds_a<0>(As1, rA, cb, af); stage_half(pA, lda, kN2, As0, 0, wid); PH_TAIL(0, BB);
    ds_a<1>(As1, rA, cb, af); stage_half(pA, lda, kN2, As0, 1, wid); PH_TAIL(1, BB);
    ds_a<2>(As1, rA, cb, af); stage_half(pB, ldb, kB3, Bs1, 0, wid); PH_TAIL(2, BB);
    // P8: ensure buf0 (A,B of T2i+2) landed; read B(T2i+2) -> BA
    WAIT_VM(2);
    ds_a<3>(As1, rA, cb, af); ds_b(Bs0, rB, cb, BA);
    stage_half(pB, ldb, kB3, Bs1, 1, wid); PH_TAIL(3, BB);
  }
  // drain: T(NT-2) in buf0 (BA ready), T(NT-1): B in buf1.B, A staged now
  const long long kL = (long long)(NT - 1) * 64;
  ds_a<0>(As0, rA, cb, af); stage_half(pA, lda, kL, As1, 0, wid); PH_TAIL(0, BA);
  ds_a<1>(As0, rA, cb, af); stage_half(pA, lda, kL, As1, 1, wid); PH_TAIL(1, BA);
  ds_a<2>(As0, rA, cb, af); PH_TAIL(2, BA);
  WAIT_VM(0);
  ds_a<3>(As0, rA, cb, af); ds_b(Bs1, rB, cb, BB); PH_TAIL(3, BA);
  ds_a<0>(As1, rA, cb, af); PH_TAIL(0, BB);
  ds_a<1>(As1, rA, cb, af); PH_TAIL(1, BB);
  ds_a<2>(As1, rA, cb, af); PH_TAIL(2, BB);
  ds_a<3>(As1, rA, cb, af); PH_TAIL(3, BB);
}

// per-thread setup shared by all kernels
struct TC {
  int wid, lane, wm, wn, rA, rB, cb, rr, ccl, rowt, colg;
};
__device__ __forceinline__ TC tc_setup() {
  TC t;
  const int tid = threadIdx.x;
  t.wid = tid >> 6;
  t.lane = tid & 63;
  t.wm = t.wid >> 2;
  t.wn = t.wid & 3;
  const int l16 = t.lane & 15;
  t.rA = t.wm * 128 + l16;
  t.rB = t.wn * 64 + l16;
  t.cb = (t.lane >> 4) * 16;
  t.rr = (t.lane >> 4) * 4;
  t.ccl = l16;
  t.rowt = tid >> 3;
  t.colg = ((tid & 7) * 8) ^ (((tid >> 3) & 4) ? 16 : 0);
  return t;
}

#define SHARED_TILES() \
  __shared__ __align__(16) unsigned short As0[16384], As1[16384]; \
  __shared__ __align__(16) unsigned short Bs0[16384], Bs1[16384]

// ---- QK fused projection: C[16384][2048] -> Q | K ----
__global__ __launch_bounds__(512, 2) void qk_kernel(
    const unsigned short* __restrict__ X, const unsigned short* __restrict__ W,
    const float* __restrict__ bq, const float* __restrict__ bk,
    unsigned short* __restrict__ Q, unsigned short* __restrict__ K) {
  SHARED_TILES();
  const int lin = blockIdx.y * 8 + blockIdx.x;
  const int swz = (lin & 7) * 64 + (lin >> 3);
  const int m0 = (swz >> 3) * 256, n0 = (swz & 7) * 256;
  TC t = tc_setup();
  const unsigned short* pA = X + (long long)(m0 + t.rowt) * HD + t.colg;
  const unsigned short* pB = W + (long long)(n0 + t.rowt) * HD + t.colg;
  f32x4 acc[8][4] = {};
  run_tile(pA, pB, HD, HD, 16, As0, As1, Bs0, Bs1, t.wid, t.rA, t.rB, t.cb, acc);
#pragma unroll
  for (int mi = 0; mi < 8; ++mi)
#pragma unroll
    for (int ni = 0; ni < 4; ++ni) {
      const int gn = n0 + t.wn * 64 + ni * 16 + t.ccl;
      const float bias = (gn < 1024) ? bq[gn] : bk[gn - 1024];
      unsigned short* dst = (gn < 1024) ? (Q + gn) : (K + gn - 1024);
#pragma unroll
      for (int j = 0; j < 4; ++j) {
        const int gm = m0 + t.wm * 128 + mi * 16 + t.rr + j;
        dst[(long long)gm * HD] = f2bf(acc[mi][ni][j] + bias);
      }
    }
}

// ---- V^T: A=Wv[1024][1024], B=x[16384][1024]; C[d][gs] -> Vt[b][d][s] ----
__global__ __launch_bounds__(512, 2) void vt_kernel(
    const unsigned short* __restrict__ Wv, const unsigned short* __restrict__ X,
    const float* __restrict__ bv, unsigned short* __restrict__ Vt) {
  SHARED_TILES();
  const int lin = blockIdx.x;
  const int swz = (lin & 7) * 32 + (lin >> 3);
  const int m0 = (swz & 3) * 256, n0 = (swz >> 2) * 256;
  TC t = tc_setup();
  const unsigned short* pA = Wv + (long long)(m0 + t.rowt) * HD + t.colg;
  const unsigned short* pB = X + (long long)(n0 + t.rowt) * HD + t.colg;
  f32x4 acc[8][4] = {};
  run_tile(pA, pB, HD, HD, 16, As0, As1, Bs0, Bs1, t.wid, t.rA, t.rB, t.cb, acc);
#pragma unroll
  for (int mi = 0; mi < 8; ++mi)
#pragma unroll
    for (int ni = 0; ni < 4; ++ni) {
      const int gn = n0 + t.wn * 64 + ni * 16 + t.ccl;  // gs
      const long long base = (long long)(gn >> 11) * SH + (gn & 2047);
#pragma unroll
      for (int j = 0; j < 4; ++j) {
        const int gm = m0 + t.wm * 128 + mi * 16 + t.rr + j;  // d
        Vt[base + (long long)gm * SS] = f2bf(acc[mi][ni][j] + bv[gm]);
      }
    }
}

// ---- scores: lower-triangular 256^2 tiles, scaled, causal+pad mask ----
__global__ __launch_bounds__(512, 2) void scores_kernel(
    const unsigned short* __restrict__ Q, const unsigned short* __restrict__ Km,
    const int* __restrict__ mask, unsigned short* __restrict__ S) {
  SHARED_TILES();
  int tt = blockIdx.x;
  int ii = 0, base = 0;
  while (tt >= base + ii + 1) { base += ii + 1; ++ii; }
  const int jj = tt - base;
  const int m0 = ii * 256, n0 = jj * 256;
  const long long b = blockIdx.z;
  TC t = tc_setup();
  const unsigned short* pA = Q + b * SH + (long long)(m0 + t.rowt) * HD + t.colg;
  const unsigned short* pB = Km + b * SH + (long long)(n0 + t.rowt) * HD + t.colg;
  f32x4 acc[8][4] = {};
  run_tile(pA, pB, HD, HD, 16, As0, As1, Bs0, Bs1, t.wid, t.rA, t.rB, t.cb, acc);
  unsigned short* Sb = S + b * (long long)SS * SS;
  const int* mb = mask + b * SS;
#pragma unroll
  for (int mi = 0; mi < 8; ++mi)
#pragma unroll
    for (int ni = 0; ni < 4; ++ni) {
      const int gn = n0 + t.wn * 64 + ni * 16 + t.ccl;
      const int mk = mb[gn];
#pragma unroll
      for (int j = 0; j < 4; ++j) {
        const int gm = m0 + t.wm * 128 + mi * 16 + t.rr + j;
        const bool dead = (gn > gm) || (mk == 0);
        Sb[(long long)gm * SS + gn] =
            dead ? (unsigned short)0xFF80u : f2bf(acc[mi][ni][j] * 0.03125f);
      }
    }
}

// ---- PV: A=S[b], B=Vt[b]; causal K-limit per m-tile ----
__global__ __launch_bounds__(512, 2) void pv_kernel(
    const unsigned short* __restrict__ S, const unsigned short* __restrict__ Vt,
    unsigned short* __restrict__ AO) {
  SHARED_TILES();
  const int mi0 = blockIdx.x;
  const int m0 = mi0 * 256, n0 = blockIdx.y * 256;
  const int NT = 4 * (mi0 + 1);
  const long long b = blockIdx.z;
  TC t = tc_setup();
  const unsigned short* pA =
      S + b * (long long)SS * SS + (long long)(m0 + t.rowt) * SS + t.colg;
  const unsigned short* pB = Vt + b * SH + (long long)(n0 + t.rowt) * SS + t.colg;
  f32x4 acc[8][4] = {};
  run_tile(pA, pB, SS, SS, NT, As0, As1, Bs0, Bs1, t.wid, t.rA, t.rB, t.cb, acc);
#pragma unroll
  for (int mi = 0; mi < 8; ++mi)
#pragma unroll
    for (int ni = 0; ni < 4; ++ni) {
      const int gn = n0 + t.wn * 64 + ni * 16 + t.ccl;
#pragma unroll
      for (int j = 0; j < 4; ++j) {
        const int gm = m0 + t.wm * 128 + mi * 16 + t.rr + j;
        AO[(b * SS + gm) * (long long)HD + gn] = f2bf(acc[mi][ni][j]);
      }
    }
}

// ---- output projection: f32 out ----
__global__ __launch_bounds__(512, 2) void oproj_kernel(
    const unsigned short* __restrict__ AO, const unsigned short* __restrict__ W,
    const float* __restrict__ bo, float* __restrict__ out) {
  SHARED_TILES();
  const int lin = blockIdx.x;
  const int swz = (lin & 7) * 32 + (lin >> 3);
  const int n0 = (swz & 3) * 256, m0 = (swz >> 2) * 256;
  TC t = tc_setup();
  const unsigned short* pA = AO + (long long)(m0 + t.rowt) * HD + t.colg;
  const unsigned short* pB = W + (long long)(n0 + t.rowt) * HD + t.colg;
  f32x4 acc[8][4] = {};
  run_tile(pA, pB, HD, HD, 16, As0, As1, Bs0, Bs1, t.wid, t.rA, t.rB, t.cb, acc);
#pragma unroll
  for (int mi = 0; mi < 8; ++mi)
#pragma unroll
    for (int ni = 0; ni < 4; ++ni) {
      const int gn = n0 + t.wn * 64 + ni * 16 + t.ccl;
      const float bias = bo[gn];
#pragma unroll
      for (int j = 0; j < 4; ++j) {
        const int gm = m0 + t.wm * 128 + mi * 16 + t.rr + j;
        out[(long long)gm * HD + gn] = acc[mi][ni][j] + bias;
      }
    }
}

__global__ __launch_bounds__(256) void cast_kernel(
    const float* __restrict__ in, unsigned short* __restrict__ out, int n) {
  int idx = blockIdx.x * blockDim.x + threadIdx.x;
  int stride = gridDim.x * blockDim.x;
  for (int i = idx * 4; i < n; i += stride * 4) {
    float4 f = *reinterpret_cast<const float4*>(in + i);
    ushort4 o;
    o.x = f2bf(f.x); o.y = f2bf(f.y); o.z = f2bf(f.z); o.w = f2bf(f.w);
    *reinterpret_cast<ushort4*>(out + i) = o;
  }
}

// In-place per-row softmax over bf16 scores (handles unwritten upper tiles).
__global__ __launch_bounds__(256) void softmax_kernel(unsigned short* __restrict__ S) {
  const int q = blockIdx.x;
  const long long b = blockIdx.y;
  unsigned short* row = S + (b * SS + q) * (long long)SS;
  const int t = threadIdx.x;
  const int wid = t >> 6, lane = t & 63;
  __shared__ float red[4];
  __shared__ float brd[2];

  ushort4 v0 = *reinterpret_cast<const ushort4*>(&row[t * 8]);
  ushort4 v1 = *reinterpret_cast<const ushort4*>(&row[t * 8 + 4]);
  unsigned short raw[8] = {v0.x, v0.y, v0.z, v0.w, v1.x, v1.y, v1.z, v1.w};
  float f[8];
#pragma unroll
  for (int j = 0; j < 8; ++j) {
    const int k = t * 8 + j;
    f[j] = (k <= q) ? bf2f(raw[j]) : -INFINITY;
  }
  float m = -INFINITY;
#pragma unroll
  for (int j = 0; j < 8; ++j) m = fmaxf(m, f[j]);
  for (int off = 32; off > 0; off >>= 1) m = fmaxf(m, __shfl_xor(m, off));
  if (lane == 0) red[wid] = m;
  __syncthreads();
  if (t == 0) brd[0] = fmaxf(fmaxf(red[0], red[1]), fmaxf(red[2], red[3]));
  __syncthreads();
  m = brd[0];

  float e[8];
  float s = 0.0f;
#pragma unroll
  for (int j = 0; j < 8; ++j) {
    e[j] = __expf(f[j] - m);
    s += e[j];
  }
  for (int off = 32; off > 0; off >>= 1) s += __shfl_xor(s, off);
  __syncthreads();
  if (lane == 0) red[wid] = s;
  __syncthreads();
  if (t == 0) brd[1] = red[0] + red[1] + red[2] + red[3];
  __syncthreads();
  const float rinv = 1.0f / brd[1];

  unsigned short o[8];
#pragma unroll
  for (int j = 0; j < 8; ++j) o[j] = f2bf(e[j] * rinv);
  *reinterpret_cast<int4*>(&row[t * 8]) = *reinterpret_cast<int4*>(o);
}

extern "C" void kernel_launch(void* const* d_in, const int* in_sizes, int n_in,
                              void* d_out, int out_size, void* d_ws, size_t ws_size,
                              hipStream_t stream) {
  const float* x = (const float*)d_in[0];
  const int* amask = (const int*)d_in[1];
  const float* wq = (const float*)d_in[2];
  const float* bq = (const float*)d_in[3];
  const float* wk = (const float*)d_in[4];
  const float* bk = (const float*)d_in[5];
  const float* wv = (const float*)d_in[6];
  const float* bv = (const float*)d_in[7];
  const float* wo = (const float*)d_in[8];
  const float* bo = (const float*)d_in[9];
  float* out = (float*)d_out;

  const long long NX = (long long)BB * SS * HD;
  char* p = (char*)d_ws;
  unsigned short* xb = (unsigned short*)p;    p += NX * 2;
  unsigned short* wqkb = (unsigned short*)p;  p += 2LL * HD * HD * 2;
  unsigned short* wvb = (unsigned short*)p;   p += (long long)HD * HD * 2;
  unsigned short* wob = (unsigned short*)p;   p += (long long)HD * HD * 2;
  unsigned short* Qb = (unsigned short*)p;    p += NX * 2;
  unsigned short* Kb = (unsigned short*)p;    p += NX * 2;
  unsigned short* Vtb = (unsigned short*)p;   p += NX * 2;  // [b][d][s]
  unsigned short* Sb = (unsigned short*)p;    p += (long long)BB * SS * SS * 2;
  unsigned short* AOb = xb;  // alias: x dead after QK+Vt projections

  cast_kernel<<<dim3(2048), 256, 0, stream>>>(x, xb, (int)NX);
  cast_kernel<<<dim3(256), 256, 0, stream>>>(wq, wqkb, HD * HD);
  cast_kernel<<<dim3(256), 256, 0, stream>>>(wk, wqkb + HD * HD, HD * HD);
  cast_kernel<<<dim3(256), 256, 0, stream>>>(wv, wvb, HD * HD);
  cast_kernel<<<dim3(256), 256, 0, stream>>>(wo, wob, HD * HD);

  qk_kernel<<<dim3(8, 64), 512, 0, stream>>>(xb, wqkb, bq, bk, Qb, Kb);
  vt_kernel<<<dim3(256), 512, 0, stream>>>(wvb, xb, bv, Vtb);

  scores_kernel<<<dim3(36, 1, BB), 512, 0, stream>>>(Qb, Kb, amask, Sb);
  softmax_kernel<<<dim3(SS, BB), 256, 0, stream>>>(Sb);
  pv_kernel<<<dim3(8, 4, BB), 512, 0, stream>>>(Sb, Vtb, AOb);

  oproj_kernel<<<dim3(256), 512, 0, stream>>>(AOb, wob, bo, out);
}